// Round 1
// baseline (125.657 us; speedup 1.0000x reference)
//
#include <hip/hip_runtime.h>
#include <hip/hip_bf16.h>

#define N_NODES 50000
#define HID     256
#define N_EDGES 300000

typedef __attribute__((ext_vector_type(8))) short bf16x8;
typedef __attribute__((ext_vector_type(4))) float f32x4;

__device__ __forceinline__ unsigned short f2bf(float f) {
  unsigned int u = __float_as_uint(f);
  u = (u + 0x7FFFu + ((u >> 16) & 1u)) >> 16;   // RNE
  return (unsigned short)u;
}
__device__ __forceinline__ float bf2f(unsigned short h) {
  return __uint_as_float(((unsigned int)h) << 16);
}

// ---- kernel 1: WcatT[j][k] bf16, j in [0,512): j<256 -> W1[k][j], else W1[256+k][j-256]
__global__ void pack_w_kernel(const float* __restrict__ W1, unsigned short* __restrict__ Wt) {
  int j = blockIdx.x;      // 0..511
  int k = threadIdx.x;     // 0..255
  float v = (j < HID) ? W1[k * HID + j] : W1[(HID + k) * HID + (j - HID)];
  Wt[j * HID + k] = f2bf(v);
}

// ---- kernel 2: P[n][512] = E[n][0:256] @ Wcat  (+ b1 on cols 0..255), bf16 out
// 128x128 tile, K=256 in 4 K-tiles of 64, 4 waves each computing 64x64.
__global__ __launch_bounds__(256) void gemm_kernel(
    const float* __restrict__ E, const unsigned short* __restrict__ Wt,
    const float* __restrict__ b1, unsigned short* __restrict__ P) {
  __shared__ alignas(16) char lds[32768];   // As 16KB | Bs 16KB, XOR-swizzled
  const int tid  = threadIdx.x;
  const int row0 = blockIdx.x * 128;
  const int col0 = blockIdx.y * 128;
  const int lane = tid & 63;
  const int wid  = tid >> 6;
  const int wr = wid >> 1, wc = wid & 1;

  f32x4 acc[4][4] = {};

  for (int kt = 0; kt < 4; ++kt) {
    // stage A (fp32->bf16 convert) and B (bf16) into swizzled LDS
#pragma unroll
    for (int it = 0; it < 4; ++it) {
      int g  = tid + it * 256;           // granule id: 128 rows x 8 granules of 16B
      int r  = g >> 3;
      int gc = g & 7;
      int swzoff = r * 128 + ((gc * 16) ^ ((r & 7) << 4));
      // A granule: row row0+r, k elems kt*64 + gc*8 .. +8
      int grow = row0 + r;
      float4 f0, f1;
      if (grow < N_NODES) {
        const float4* src = reinterpret_cast<const float4*>(E + (size_t)grow * HID + kt * 64 + gc * 8);
        f0 = src[0]; f1 = src[1];
      } else {
        f0 = make_float4(0.f, 0.f, 0.f, 0.f); f1 = f0;
      }
      bf16x8 pk;
      pk[0] = (short)f2bf(f0.x); pk[1] = (short)f2bf(f0.y);
      pk[2] = (short)f2bf(f0.z); pk[3] = (short)f2bf(f0.w);
      pk[4] = (short)f2bf(f1.x); pk[5] = (short)f2bf(f1.y);
      pk[6] = (short)f2bf(f1.z); pk[7] = (short)f2bf(f1.w);
      *reinterpret_cast<bf16x8*>(&lds[swzoff]) = pk;
      // B granule: WcatT row col0+r (bf16, contiguous)
      bf16x8 bsrc = *reinterpret_cast<const bf16x8*>(Wt + (size_t)(col0 + r) * HID + kt * 64 + gc * 8);
      *reinterpret_cast<bf16x8*>(&lds[16384 + swzoff]) = bsrc;
    }
    __syncthreads();
#pragma unroll
    for (int ks = 0; ks < 2; ++ks) {
      bf16x8 a[4], b[4];
      int kb = ks * 64 + ((lane >> 4) << 4);   // byte offset of lane's 8 bf16 along K
#pragma unroll
      for (int m = 0; m < 4; ++m) {
        int r = wr * 64 + m * 16 + (lane & 15);
        a[m] = *reinterpret_cast<bf16x8*>(&lds[r * 128 + (kb ^ ((r & 7) << 4))]);
      }
#pragma unroll
      for (int n = 0; n < 4; ++n) {
        int c = wc * 64 + n * 16 + (lane & 15);
        b[n] = *reinterpret_cast<bf16x8*>(&lds[16384 + c * 128 + (kb ^ ((c & 7) << 4))]);
      }
#pragma unroll
      for (int m = 0; m < 4; ++m)
#pragma unroll
        for (int n = 0; n < 4; ++n)
          acc[m][n] = __builtin_amdgcn_mfma_f32_16x16x32_bf16(a[m], b[n], acc[m][n], 0, 0, 0);
    }
    __syncthreads();
  }

  // epilogue: C/D layout col=lane&15, row=(lane>>4)*4+reg  [m89]
#pragma unroll
  for (int n = 0; n < 4; ++n) {
    int col = col0 + wc * 64 + n * 16 + (lane & 15);
    float badd = (col < HID) ? b1[col] : 0.0f;
#pragma unroll
    for (int m = 0; m < 4; ++m) {
      int rbase = row0 + wr * 64 + m * 16 + ((lane >> 4) << 2);
#pragma unroll
      for (int r = 0; r < 4; ++r) {
        int gr = rbase + r;
        if (gr < N_NODES)
          P[(size_t)gr * 512 + col] = f2bf(acc[m][n][r] + badd);
      }
    }
  }
}

// ---- kernel 3: per edge, gather two 512B bf16 rows, relu-add, dot W2
__global__ __launch_bounds__(256) void edge_kernel(
    const int* __restrict__ idx, const unsigned short* __restrict__ P,
    const float* __restrict__ W2, const float* __restrict__ b2,
    float* __restrict__ out) {
  const int lane = threadIdx.x & 63;
  const int gw = blockIdx.x * 4 + (threadIdx.x >> 6);
  const int stride = gridDim.x * 4;
  const float4 w2 = *reinterpret_cast<const float4*>(W2 + lane * 4);
  const float bias = b2[0];
  for (int e = gw; e < N_EDGES; e += stride) {
    int s = idx[e];
    int t = idx[N_EDGES + e];
    ushort4 av = *reinterpret_cast<const ushort4*>(P + (size_t)s * 512 + lane * 4);
    ushort4 bv = *reinterpret_cast<const ushort4*>(P + (size_t)t * 512 + 256 + lane * 4);
    float h0 = fmaxf(bf2f(av.x) + bf2f(bv.x), 0.f);
    float h1 = fmaxf(bf2f(av.y) + bf2f(bv.y), 0.f);
    float h2 = fmaxf(bf2f(av.z) + bf2f(bv.z), 0.f);
    float h3 = fmaxf(bf2f(av.w) + bf2f(bv.w), 0.f);
    float acc = h0 * w2.x + h1 * w2.y + h2 * w2.z + h3 * w2.w;
#pragma unroll
    for (int off = 32; off > 0; off >>= 1)
      acc += __shfl_xor(acc, off, 64);
    if (lane == 0) out[e] = acc + bias;
  }
}

extern "C" void kernel_launch(void* const* d_in, const int* in_sizes, int n_in,
                              void* d_out, int out_size, void* d_ws, size_t ws_size,
                              hipStream_t stream) {
  const float* E  = (const float*)d_in[0];
  const int*   idx = (const int*)d_in[1];
  const float* W1 = (const float*)d_in[2];
  const float* b1 = (const float*)d_in[3];
  const float* W2 = (const float*)d_in[4];
  const float* b2 = (const float*)d_in[5];
  float* out = (float*)d_out;

  unsigned short* Wt = (unsigned short*)d_ws;                          // 512*256*2   = 256 KiB
  unsigned short* P  = (unsigned short*)((char*)d_ws + 512 * HID * 2); // 50000*512*2 = 48.8 MiB

  hipLaunchKernelGGL(pack_w_kernel, dim3(2 * HID), dim3(HID), 0, stream, W1, Wt);
  hipLaunchKernelGGL(gemm_kernel, dim3((N_NODES + 127) / 128, 4), dim3(256), 0, stream, E, Wt, b1, P);
  hipLaunchKernelGGL(edge_kernel, dim3(2048), dim3(256), 0, stream, idx, P, W2, b2, out);
}

// Round 2
// 119.169 us; speedup vs baseline: 1.0544x; 1.0544x over previous
//
#include <hip/hip_runtime.h>
#include <hip/hip_bf16.h>

#define N_NODES 50000
#define HID     256
#define N_EDGES 300000

typedef __attribute__((ext_vector_type(8))) short bf16x8;
typedef __attribute__((ext_vector_type(4))) float f32x4;

__device__ __forceinline__ unsigned short f2bf(float f) {
  unsigned int u = __float_as_uint(f);
  u = (u + 0x7FFFu + ((u >> 16) & 1u)) >> 16;   // RNE
  return (unsigned short)u;
}
__device__ __forceinline__ float bflo(unsigned int u) { return __uint_as_float(u << 16); }
__device__ __forceinline__ float bfhi(unsigned int u) { return __uint_as_float(u & 0xFFFF0000u); }

// ---- kernel 1: Wcat^T in MFMA-fragment order.
// Logical Wt[j][k] (j=P-col 0..511, k=0..255): j<256 -> W1[k][j], else W1[256+k][j-256].
// Fragment layout: frag f = (j>>4)*8 + (k>>5); lane = (j&15) | (((k>>3)&3)<<4); elem = k&7.
// Wtf[f*512 + lane*8 + elem]. A-frag load in gemm is then lane-contiguous (1KB/wave).
__global__ void pack_w_kernel(const float* __restrict__ W1, unsigned short* __restrict__ Wtf) {
  int j = blockIdx.x;      // 0..511
  int k = threadIdx.x;     // 0..255
  float v = (j < HID) ? W1[k * HID + j] : W1[(HID + k) * HID + (j - HID)];
  int f    = (j >> 4) * 8 + (k >> 5);
  int lane = (j & 15) | (((k >> 3) & 3) << 4);
  int elem = k & 7;
  Wtf[f * 512 + lane * 8 + elem] = f2bf(v);
}

// ---- kernel 2: P[node][512] = E[node][0:256] @ Wcat (+b1 on cols 0..255), bf16 out.
// One block = 128 nodes x full 512 cols; E staged ONCE in 64KB swizzled LDS.
// Operands swapped: A = Wt (M = P-cols), B = E (N = nodes) so D rows = P-cols ->
// each lane stores 4 consecutive P-cols of one node as ushort4 (coalescing-friendly).
__global__ __launch_bounds__(256) void gemm_kernel(
    const float* __restrict__ E, const unsigned short* __restrict__ Wtf,
    const float* __restrict__ b1, unsigned short* __restrict__ P) {
  __shared__ alignas(16) char lds[65536];   // E-tile: 128 rows x 512B (bf16), XOR-swizzled
  const int tid  = threadIdx.x;
  const int lane = tid & 63;
  const int wid  = tid >> 6;
  const int wm   = wid >> 1;   // col half (0..1): 64 P-cols per ct
  const int wn   = wid & 1;    // node half (0..1): 64 nodes
  const int row0 = blockIdx.x * 128;

  // ---- stage E tile fp32 -> bf16 into swizzled LDS (once) ----
#pragma unroll
  for (int it = 0; it < 16; ++it) {
    int g  = tid + it * 256;       // 4096 granules of 16B
    int r  = g >> 5;               // row 0..127
    int gc = g & 31;               // 16B granule within row
    int grow = row0 + r;
    float4 f0, f1;
    if (grow < N_NODES) {
      const float4* src = reinterpret_cast<const float4*>(E + (size_t)grow * HID + gc * 8);
      f0 = src[0]; f1 = src[1];
    } else {
      f0 = make_float4(0.f, 0.f, 0.f, 0.f); f1 = f0;
    }
    bf16x8 pk;
    pk[0] = (short)f2bf(f0.x); pk[1] = (short)f2bf(f0.y);
    pk[2] = (short)f2bf(f0.z); pk[3] = (short)f2bf(f0.w);
    pk[4] = (short)f2bf(f1.x); pk[5] = (short)f2bf(f1.y);
    pk[6] = (short)f2bf(f1.z); pk[7] = (short)f2bf(f1.w);
    *reinterpret_cast<bf16x8*>(&lds[r * 512 + ((gc * 16) ^ ((r & 7) << 4))]) = pk;
  }
  __syncthreads();

  // ---- 4 column-tiles of 128 P-cols each ----
  for (int ct = 0; ct < 4; ++ct) {
    f32x4 acc[4][4] = {};
#pragma unroll
    for (int kk = 0; kk < 8; ++kk) {           // K-step of 32
      int kb = kk * 64 + ((lane >> 4) << 4);   // byte offset of lane's 8 bf16 along K
      bf16x8 a[4], b[4];
#pragma unroll
      for (int m = 0; m < 4; ++m) {
        int f = (ct * 8 + wm * 4 + m) * 8 + kk;
        a[m] = *reinterpret_cast<const bf16x8*>(Wtf + f * 512 + lane * 8);  // coalesced 1KB
      }
#pragma unroll
      for (int n = 0; n < 4; ++n) {
        int r = wn * 64 + n * 16 + (lane & 15);
        b[n] = *reinterpret_cast<bf16x8*>(&lds[r * 512 + (kb ^ ((r & 7) << 4))]);
      }
#pragma unroll
      for (int m = 0; m < 4; ++m)
#pragma unroll
        for (int n = 0; n < 4; ++n)
          acc[m][n] = __builtin_amdgcn_mfma_f32_16x16x32_bf16(a[m], b[n], acc[m][n], 0, 0, 0);
    }
    // ---- epilogue: D col = node (lane&15), D rows = 4 consecutive P-cols ----
#pragma unroll
    for (int m = 0; m < 4; ++m) {
      int pcb = ct * 128 + wm * 64 + m * 16 + ((lane >> 4) << 2);  // P-col base (x4)
      float4 bv = make_float4(0.f, 0.f, 0.f, 0.f);
      if (ct < 2) bv = *reinterpret_cast<const float4*>(b1 + pcb); // cols<256 <=> ct<2
#pragma unroll
      for (int n = 0; n < 4; ++n) {
        int node = row0 + wn * 64 + n * 16 + (lane & 15);
        if (node < N_NODES) {
          ushort4 o;
          o.x = f2bf(acc[m][n][0] + bv.x);
          o.y = f2bf(acc[m][n][1] + bv.y);
          o.z = f2bf(acc[m][n][2] + bv.z);
          o.w = f2bf(acc[m][n][3] + bv.w);
          *reinterpret_cast<ushort4*>(P + (size_t)node * 512 + pcb) = o;
        }
      }
    }
  }
}

// ---- kernel 3: 2 edges per wave (32 lanes each), 16B bf16x8 gathers.
__global__ __launch_bounds__(256) void edge_kernel(
    const int* __restrict__ idx, const unsigned short* __restrict__ P,
    const float* __restrict__ W2, const float* __restrict__ b2,
    float* __restrict__ out) {
  const int tid  = threadIdx.x;
  const int lane = tid & 63;
  const int l32  = lane & 31;
  const int half = lane >> 5;
  const int wv     = blockIdx.x * 4 + (tid >> 6);
  const int nwaves = gridDim.x * 4;
  const float4 w0 = *reinterpret_cast<const float4*>(W2 + l32 * 8);
  const float4 w1 = *reinterpret_cast<const float4*>(W2 + l32 * 8 + 4);
  const float bias = b2[0];
  for (int ep = wv; ep < N_EDGES / 2; ep += nwaves) {
    int e = ep * 2 + half;
    int s = idx[e];
    int t = idx[N_EDGES + e];
    uint4 ua = *reinterpret_cast<const uint4*>(P + (size_t)s * 512 + l32 * 8);
    uint4 ub = *reinterpret_cast<const uint4*>(P + (size_t)t * 512 + 256 + l32 * 8);
    float h0 = fmaxf(bflo(ua.x) + bflo(ub.x), 0.f);
    float h1 = fmaxf(bfhi(ua.x) + bfhi(ub.x), 0.f);
    float h2 = fmaxf(bflo(ua.y) + bflo(ub.y), 0.f);
    float h3 = fmaxf(bfhi(ua.y) + bfhi(ub.y), 0.f);
    float h4 = fmaxf(bflo(ua.z) + bflo(ub.z), 0.f);
    float h5 = fmaxf(bfhi(ua.z) + bfhi(ub.z), 0.f);
    float h6 = fmaxf(bflo(ua.w) + bflo(ub.w), 0.f);
    float h7 = fmaxf(bfhi(ua.w) + bfhi(ub.w), 0.f);
    float acc = h0 * w0.x + h1 * w0.y + h2 * w0.z + h3 * w0.w
              + h4 * w1.x + h5 * w1.y + h6 * w1.z + h7 * w1.w;
#pragma unroll
    for (int off = 1; off < 32; off <<= 1)
      acc += __shfl_xor(acc, off, 64);   // stays within each 32-lane half
    if (l32 == 0) out[e] = acc + bias;
  }
}

extern "C" void kernel_launch(void* const* d_in, const int* in_sizes, int n_in,
                              void* d_out, int out_size, void* d_ws, size_t ws_size,
                              hipStream_t stream) {
  const float* E   = (const float*)d_in[0];
  const int*   idx = (const int*)d_in[1];
  const float* W1  = (const float*)d_in[2];
  const float* b1  = (const float*)d_in[3];
  const float* W2  = (const float*)d_in[4];
  const float* b2  = (const float*)d_in[5];
  float* out = (float*)d_out;

  unsigned short* Wtf = (unsigned short*)d_ws;                          // 256 KiB
  unsigned short* P   = (unsigned short*)((char*)d_ws + 512 * HID * 2); // 48.8 MiB

  hipLaunchKernelGGL(pack_w_kernel, dim3(2 * HID), dim3(HID), 0, stream, W1, Wtf);
  hipLaunchKernelGGL(gemm_kernel, dim3((N_NODES + 127) / 128), dim3(256), 0, stream, E, Wtf, b1, P);
  hipLaunchKernelGGL(edge_kernel, dim3(2048), dim3(256), 0, stream, idx, P, W2, b2, out);
}

// Round 3
// 116.161 us; speedup vs baseline: 1.0817x; 1.0259x over previous
//
#include <hip/hip_runtime.h>
#include <hip/hip_bf16.h>

#define N_NODES 50000
#define HID     256
#define N_EDGES 300000

typedef __attribute__((ext_vector_type(8))) short bf16x8;
typedef __attribute__((ext_vector_type(4))) float f32x4;

__device__ __forceinline__ unsigned short f2bf(float f) {
  unsigned int u = __float_as_uint(f);
  u = (u + 0x7FFFu + ((u >> 16) & 1u)) >> 16;   // RNE
  return (unsigned short)u;
}
__device__ __forceinline__ float bflo(unsigned int u) { return __uint_as_float(u << 16); }
__device__ __forceinline__ float bfhi(unsigned int u) { return __uint_as_float(u & 0xFFFF0000u); }

// ---- kernel 1: Wcat^T in MFMA-fragment order (coalesced reads).
// Logical Wt[j][k]: j<256 -> W1[k][j], else W1[256+k][j-256].
// Fragment layout: f = (j>>4)*8 + (k>>5); lane = (j&15) | (((k>>3)&3)<<4); elem = k&7.
__global__ __launch_bounds__(128) void pack_w_kernel(
    const float* __restrict__ W1, unsigned short* __restrict__ Wtf) {
  int k = blockIdx.x;          // 0..255
  int t = threadIdx.x;         // 0..127
  int half = t >> 6;           // 0: j in [0,256) reads W1 row k; 1: j in [256,512) reads row 256+k
  int jj = (t & 63) * 4;
  const float4 v = *reinterpret_cast<const float4*>(
      W1 + (size_t)(half ? (HID + k) : k) * HID + jj);
  float vv[4] = {v.x, v.y, v.z, v.w};
#pragma unroll
  for (int e = 0; e < 4; ++e) {
    int j = half * HID + jj + e;
    int f    = (j >> 4) * 8 + (k >> 5);
    int lane = (j & 15) | (((k >> 3) & 3) << 4);
    int elem = k & 7;
    Wtf[f * 512 + lane * 8 + elem] = f2bf(vv[e]);
  }
}

// ---- kernel 2: P[node][512] = E[node] @ Wcat (+b1 on cols<256), bf16 out.
// 64 nodes x 512 cols per block -> 782 blocks, 32KB LDS, ~3 blocks/CU.
// E b-fragments hoisted to registers once; inner loop = Wtf a-load (L2) + MFMA only.
__global__ __launch_bounds__(256, 3) void gemm_kernel(
    const float* __restrict__ E, const unsigned short* __restrict__ Wtf,
    const float* __restrict__ b1, unsigned short* __restrict__ P) {
  __shared__ alignas(16) char lds[32768];   // 64 rows x 512B bf16, XOR-swizzled
  const int tid  = threadIdx.x;
  const int lane = tid & 63;
  const int wid  = tid >> 6;
  const int wm   = wid >> 1;   // col half within ct (64 cols)
  const int wn   = wid & 1;    // node half (32 nodes)
  const int row0 = blockIdx.x * 64;

  // ---- stage E tile fp32 -> bf16 swizzled (once) ----
#pragma unroll
  for (int it = 0; it < 8; ++it) {
    int g  = tid + it * 256;       // 2048 granules of 16B
    int r  = g >> 5;               // row 0..63
    int gc = g & 31;
    int grow = row0 + r;
    float4 f0, f1;
    if (grow < N_NODES) {
      const float4* src = reinterpret_cast<const float4*>(E + (size_t)grow * HID + gc * 8);
      f0 = src[0]; f1 = src[1];
    } else {
      f0 = make_float4(0.f, 0.f, 0.f, 0.f); f1 = f0;
    }
    bf16x8 pk;
    pk[0] = (short)f2bf(f0.x); pk[1] = (short)f2bf(f0.y);
    pk[2] = (short)f2bf(f0.z); pk[3] = (short)f2bf(f0.w);
    pk[4] = (short)f2bf(f1.x); pk[5] = (short)f2bf(f1.y);
    pk[6] = (short)f2bf(f1.z); pk[7] = (short)f2bf(f1.w);
    *reinterpret_cast<bf16x8*>(&lds[r * 512 + ((gc * 16) ^ ((r & 7) << 4))]) = pk;
  }
  __syncthreads();

  // ---- hoist all E b-fragments for this wave: 8 kk x 2 n (64 VGPR) ----
  bf16x8 bfr[8][2];
#pragma unroll
  for (int kk = 0; kk < 8; ++kk) {
    int kb = kk * 64 + ((lane >> 4) << 4);
#pragma unroll
    for (int n = 0; n < 2; ++n) {
      int r = wn * 32 + n * 16 + (lane & 15);
      bfr[kk][n] = *reinterpret_cast<bf16x8*>(&lds[r * 512 + (kb ^ ((r & 7) << 4))]);
    }
  }

  // ---- 4 column tiles of 128 P-cols; wave covers 64 of them ----
#pragma unroll
  for (int ct = 0; ct < 4; ++ct) {
    f32x4 acc[4][2] = {};
#pragma unroll
    for (int kk = 0; kk < 8; ++kk) {
      bf16x8 a[4];
#pragma unroll
      for (int m = 0; m < 4; ++m) {
        int f = (ct * 8 + wm * 4 + m) * 8 + kk;
        a[m] = *reinterpret_cast<const bf16x8*>(Wtf + (size_t)f * 512 + lane * 8); // 1KB coalesced, L2
      }
#pragma unroll
      for (int m = 0; m < 4; ++m)
#pragma unroll
        for (int n = 0; n < 2; ++n)
          acc[m][n] = __builtin_amdgcn_mfma_f32_16x16x32_bf16(a[m], bfr[kk][n], acc[m][n], 0, 0, 0);
    }
    // ---- epilogue: lane stores node (lane&15), 4 consecutive P-cols as ushort4 ----
#pragma unroll
    for (int m = 0; m < 4; ++m) {
      int fm  = ct * 8 + wm * 4 + m;
      int pcb = fm * 16 + ((lane >> 4) << 2);
      float4 bv = make_float4(0.f, 0.f, 0.f, 0.f);
      if (fm < 16) bv = *reinterpret_cast<const float4*>(b1 + pcb);
#pragma unroll
      for (int n = 0; n < 2; ++n) {
        int node = row0 + wn * 32 + n * 16 + (lane & 15);
        if (node < N_NODES) {
          ushort4 o;
          o.x = f2bf(acc[m][n][0] + bv.x);
          o.y = f2bf(acc[m][n][1] + bv.y);
          o.z = f2bf(acc[m][n][2] + bv.z);
          o.w = f2bf(acc[m][n][3] + bv.w);
          *reinterpret_cast<ushort4*>(P + (size_t)node * 512 + pcb) = o;
        }
      }
    }
  }
}

// ---- kernel 3: 2 edges per wave (32 lanes each), 16B bf16x8 gathers.
__global__ __launch_bounds__(256) void edge_kernel(
    const int* __restrict__ idx, const unsigned short* __restrict__ P,
    const float* __restrict__ W2, const float* __restrict__ b2,
    float* __restrict__ out) {
  const int tid  = threadIdx.x;
  const int lane = tid & 63;
  const int l32  = lane & 31;
  const int half = lane >> 5;
  const int wv     = blockIdx.x * 4 + (tid >> 6);
  const int nwaves = gridDim.x * 4;
  const float4 w0 = *reinterpret_cast<const float4*>(W2 + l32 * 8);
  const float4 w1 = *reinterpret_cast<const float4*>(W2 + l32 * 8 + 4);
  const float bias = b2[0];
  for (int ep = wv; ep < N_EDGES / 2; ep += nwaves) {
    int e = ep * 2 + half;
    int s = idx[e];
    int t = idx[N_EDGES + e];
    uint4 ua = *reinterpret_cast<const uint4*>(P + (size_t)s * 512 + l32 * 8);
    uint4 ub = *reinterpret_cast<const uint4*>(P + (size_t)t * 512 + 256 + l32 * 8);
    float h0 = fmaxf(bflo(ua.x) + bflo(ub.x), 0.f);
    float h1 = fmaxf(bfhi(ua.x) + bfhi(ub.x), 0.f);
    float h2 = fmaxf(bflo(ua.y) + bflo(ub.y), 0.f);
    float h3 = fmaxf(bfhi(ua.y) + bfhi(ub.y), 0.f);
    float h4 = fmaxf(bflo(ua.z) + bflo(ub.z), 0.f);
    float h5 = fmaxf(bfhi(ua.z) + bfhi(ub.z), 0.f);
    float h6 = fmaxf(bflo(ua.w) + bflo(ub.w), 0.f);
    float h7 = fmaxf(bfhi(ua.w) + bfhi(ub.w), 0.f);
    float acc = h0 * w0.x + h1 * w0.y + h2 * w0.z + h3 * w0.w
              + h4 * w1.x + h5 * w1.y + h6 * w1.z + h7 * w1.w;
#pragma unroll
    for (int off = 1; off < 32; off <<= 1)
      acc += __shfl_xor(acc, off, 64);   // stays within each 32-lane half
    if (l32 == 0) out[e] = acc + bias;
  }
}

extern "C" void kernel_launch(void* const* d_in, const int* in_sizes, int n_in,
                              void* d_out, int out_size, void* d_ws, size_t ws_size,
                              hipStream_t stream) {
  const float* E   = (const float*)d_in[0];
  const int*   idx = (const int*)d_in[1];
  const float* W1  = (const float*)d_in[2];
  const float* b1  = (const float*)d_in[3];
  const float* W2  = (const float*)d_in[4];
  const float* b2  = (const float*)d_in[5];
  float* out = (float*)d_out;

  unsigned short* Wtf = (unsigned short*)d_ws;                          // 256 KiB
  unsigned short* P   = (unsigned short*)((char*)d_ws + 512 * HID * 2); // 48.8 MiB

  hipLaunchKernelGGL(pack_w_kernel, dim3(HID), dim3(128), 0, stream, W1, Wtf);
  hipLaunchKernelGGL(gemm_kernel, dim3((N_NODES + 63) / 64), dim3(256), 0, stream, E, Wtf, b1, P);
  hipLaunchKernelGGL(edge_kernel, dim3(2048), dim3(256), 0, stream, idx, P, W2, b2, out);
}

// Round 4
// 81.079 us; speedup vs baseline: 1.5498x; 1.4327x over previous
//
#include <hip/hip_runtime.h>
#include <hip/hip_bf16.h>

#define N_NODES 50000
#define HID     256
#define N_EDGES 300000
#define NT      32   // nodes per GEMM tile

typedef __attribute__((ext_vector_type(8))) short bf16x8;
typedef __attribute__((ext_vector_type(4))) float f32x4;

__device__ __forceinline__ unsigned short f2bf(float f) {
  unsigned int u = __float_as_uint(f);
  u = (u + 0x7FFFu + ((u >> 16) & 1u)) >> 16;   // RNE
  return (unsigned short)u;
}
__device__ __forceinline__ float bflo(unsigned int u) { return __uint_as_float(u << 16); }
__device__ __forceinline__ float bfhi(unsigned int u) { return __uint_as_float(u & 0xFFFF0000u); }

__device__ __forceinline__ bf16x8 cvt8(float4 u, float4 v) {
  bf16x8 r;
  r[0] = (short)f2bf(u.x); r[1] = (short)f2bf(u.y);
  r[2] = (short)f2bf(u.z); r[3] = (short)f2bf(u.w);
  r[4] = (short)f2bf(v.x); r[5] = (short)f2bf(v.y);
  r[6] = (short)f2bf(v.z); r[7] = (short)f2bf(v.w);
  return r;
}

// ---- kernel 1: Wcat^T in MFMA-fragment order (coalesced reads).
// Logical Wt[j][k]: j<256 -> W1[k][j], else W1[256+k][j-256].
// Fragment layout: f = (j>>4)*8 + (k>>5); lane = (j&15) | (((k>>3)&3)<<4); elem = k&7.
__global__ __launch_bounds__(128) void pack_w_kernel(
    const float* __restrict__ W1, unsigned short* __restrict__ Wtf) {
  int k = blockIdx.x;          // 0..255
  int t = threadIdx.x;         // 0..127
  int half = t >> 6;
  int jj = (t & 63) * 4;
  const float4 v = *reinterpret_cast<const float4*>(
      W1 + (size_t)(half ? (HID + k) : k) * HID + jj);
  float vv[4] = {v.x, v.y, v.z, v.w};
#pragma unroll
  for (int e = 0; e < 4; ++e) {
    int j = half * HID + jj + e;
    int f    = (j >> 4) * 8 + (k >> 5);
    int lane = (j & 15) | (((k >> 3) & 3) << 4);
    int elem = k & 7;
    Wtf[f * 512 + lane * 8 + elem] = f2bf(vv[e]);
  }
}

// ---- kernel 2: weights-stationary streaming GEMM.
// 8 waves/block; wave w holds A-frags for P-cols [w*64, w*64+64) x K=256 in 128 VGPRs.
// 32-node E tiles stream through double-buffered LDS (async-split staging).
__global__ __launch_bounds__(512, 2) void gemm_kernel(
    const float* __restrict__ E, const unsigned short* __restrict__ Wtf,
    const float* __restrict__ b1, unsigned short* __restrict__ P) {
  __shared__ alignas(16) char lds[2][16384];   // 32 rows x 512B bf16, XOR-swizzled
  const int tid  = threadIdx.x;
  const int lane = tid & 63;
  const int w    = tid >> 6;                   // 0..7

  // ---- persistent A fragments (one-time, coalesced, L2/L3) ----
  bf16x8 a[4][8];
#pragma unroll
  for (int m = 0; m < 4; ++m)
#pragma unroll
    for (int kk = 0; kk < 8; ++kk)
      a[m][kk] = *reinterpret_cast<const bf16x8*>(
          Wtf + (((size_t)(w * 4 + m) * 8 + kk) << 9) + lane * 8);

  // ---- bias (per-col, hoisted) ----
  float4 bv[4];
#pragma unroll
  for (int m = 0; m < 4; ++m) {
    int fm = w * 4 + m;
    bv[m] = (fm < 16) ? *reinterpret_cast<const float4*>(b1 + fm * 16 + ((lane >> 4) << 2))
                      : make_float4(0.f, 0.f, 0.f, 0.f);
  }

  // ---- staging geometry: thread -> (row srow, granules sg and sg+16) ----
  const int srow = tid >> 4;               // 0..31
  const int sg   = tid & 15;
  const int swz  = (srow & 7) << 4;
  const int woff0 = srow * 512 + ((sg * 16) ^ swz);
  const int woff1 = srow * 512 + (((sg + 16) * 16) ^ swz);
  const int G = gridDim.x;
  const int NTILES = (N_NODES + NT - 1) / NT;

  float4 s0, s1, s2, s3;
  int t = blockIdx.x;
  if (t >= NTILES) return;

  // ---- prologue: stage tile t into buf0, issue tile t+G ----
  {
    int grow = t * NT + srow;
    if (grow < N_NODES) {
      const float4* p = reinterpret_cast<const float4*>(E + (size_t)grow * HID + sg * 8);
      s0 = p[0]; s1 = p[1]; s2 = p[32]; s3 = p[33];
    } else { s0 = s1 = s2 = s3 = make_float4(0.f, 0.f, 0.f, 0.f); }
    *reinterpret_cast<bf16x8*>(&lds[0][woff0]) = cvt8(s0, s1);
    *reinterpret_cast<bf16x8*>(&lds[0][woff1]) = cvt8(s2, s3);
  }
  int tn = t + G;
  if (tn < NTILES) {
    int grow = tn * NT + srow;
    if (grow < N_NODES) {
      const float4* p = reinterpret_cast<const float4*>(E + (size_t)grow * HID + sg * 8);
      s0 = p[0]; s1 = p[1]; s2 = p[32]; s3 = p[33];
    } else { s0 = s1 = s2 = s3 = make_float4(0.f, 0.f, 0.f, 0.f); }
  }
  __syncthreads();

  int cur = 0;
  while (true) {
    // ---- compute tile t from lds[cur]: pure ds_read + MFMA ----
    f32x4 acc[4][2] = {};
#pragma unroll
    for (int n = 0; n < 2; ++n) {
      int r   = n * 16 + (lane & 15);
      int rb  = r * 512;
      int sw  = (r & 7) << 4;
      int kb0 = (lane >> 4) << 4;
      bf16x8 bfr[8];
#pragma unroll
      for (int kk = 0; kk < 8; ++kk)
        bfr[kk] = *reinterpret_cast<bf16x8*>(&lds[cur][rb + ((kk * 64 + kb0) ^ sw)]);
#pragma unroll
      for (int kk = 0; kk < 8; ++kk)
#pragma unroll
        for (int m = 0; m < 4; ++m)
          acc[m][n] = __builtin_amdgcn_mfma_f32_16x16x32_bf16(a[m][kk], bfr[kk], acc[m][n], 0, 0, 0);
    }
    // ---- epilogue: lane stores node (lane&15), 4 consecutive P-cols ----
#pragma unroll
    for (int m = 0; m < 4; ++m) {
      int pcb = (w * 4 + m) * 16 + ((lane >> 4) << 2);
#pragma unroll
      for (int n = 0; n < 2; ++n) {
        int node = t * NT + n * 16 + (lane & 15);
        if (node < N_NODES) {
          ushort4 o;
          o.x = f2bf(acc[m][n][0] + bv[m].x);
          o.y = f2bf(acc[m][n][1] + bv[m].y);
          o.z = f2bf(acc[m][n][2] + bv[m].z);
          o.w = f2bf(acc[m][n][3] + bv[m].w);
          *reinterpret_cast<ushort4*>(P + (size_t)node * 512 + pcb) = o;
        }
      }
    }
    if (tn >= NTILES) break;
    // ---- write staged tile tn into the other buffer, issue tn+G ----
    *reinterpret_cast<bf16x8*>(&lds[cur ^ 1][woff0]) = cvt8(s0, s1);
    *reinterpret_cast<bf16x8*>(&lds[cur ^ 1][woff1]) = cvt8(s2, s3);
    t = tn; tn = t + G;
    if (tn < NTILES) {
      int grow = tn * NT + srow;
      if (grow < N_NODES) {
        const float4* p = reinterpret_cast<const float4*>(E + (size_t)grow * HID + sg * 8);
        s0 = p[0]; s1 = p[1]; s2 = p[32]; s3 = p[33];
      } else { s0 = s1 = s2 = s3 = make_float4(0.f, 0.f, 0.f, 0.f); }
    }
    __syncthreads();
    cur ^= 1;
  }
}

// ---- kernel 3: 2 edges per wave (32 lanes each), 16B bf16x8 gathers.
__global__ __launch_bounds__(256) void edge_kernel(
    const int* __restrict__ idx, const unsigned short* __restrict__ P,
    const float* __restrict__ W2, const float* __restrict__ b2,
    float* __restrict__ out) {
  const int tid  = threadIdx.x;
  const int lane = tid & 63;
  const int l32  = lane & 31;
  const int half = lane >> 5;
  const int wv     = blockIdx.x * 4 + (tid >> 6);
  const int nwaves = gridDim.x * 4;
  const float4 w0 = *reinterpret_cast<const float4*>(W2 + l32 * 8);
  const float4 w1 = *reinterpret_cast<const float4*>(W2 + l32 * 8 + 4);
  const float bias = b2[0];
  for (int ep = wv; ep < N_EDGES / 2; ep += nwaves) {
    int e = ep * 2 + half;
    int s = idx[e];
    int t = idx[N_EDGES + e];
    uint4 ua = *reinterpret_cast<const uint4*>(P + (size_t)s * 512 + l32 * 8);
    uint4 ub = *reinterpret_cast<const uint4*>(P + (size_t)t * 512 + 256 + l32 * 8);
    float h0 = fmaxf(bflo(ua.x) + bflo(ub.x), 0.f);
    float h1 = fmaxf(bfhi(ua.x) + bfhi(ub.x), 0.f);
    float h2 = fmaxf(bflo(ua.y) + bflo(ub.y), 0.f);
    float h3 = fmaxf(bfhi(ua.y) + bfhi(ub.y), 0.f);
    float h4 = fmaxf(bflo(ua.z) + bflo(ub.z), 0.f);
    float h5 = fmaxf(bfhi(ua.z) + bfhi(ub.z), 0.f);
    float h6 = fmaxf(bflo(ua.w) + bflo(ub.w), 0.f);
    float h7 = fmaxf(bfhi(ua.w) + bfhi(ub.w), 0.f);
    float acc = h0 * w0.x + h1 * w0.y + h2 * w0.z + h3 * w0.w
              + h4 * w1.x + h5 * w1.y + h6 * w1.z + h7 * w1.w;
#pragma unroll
    for (int off = 1; off < 32; off <<= 1)
      acc += __shfl_xor(acc, off, 64);   // stays within each 32-lane half
    if (l32 == 0) out[e] = acc + bias;
  }
}

extern "C" void kernel_launch(void* const* d_in, const int* in_sizes, int n_in,
                              void* d_out, int out_size, void* d_ws, size_t ws_size,
                              hipStream_t stream) {
  const float* E   = (const float*)d_in[0];
  const int*   idx = (const int*)d_in[1];
  const float* W1  = (const float*)d_in[2];
  const float* b1  = (const float*)d_in[3];
  const float* W2  = (const float*)d_in[4];
  const float* b2  = (const float*)d_in[5];
  float* out = (float*)d_out;

  unsigned short* Wtf = (unsigned short*)d_ws;                          // 256 KiB
  unsigned short* P   = (unsigned short*)((char*)d_ws + 512 * HID * 2); // 48.8 MiB

  hipLaunchKernelGGL(pack_w_kernel, dim3(HID), dim3(128), 0, stream, W1, Wtf);
  hipLaunchKernelGGL(gemm_kernel, dim3(256), dim3(512), 0, stream, E, Wtf, b1, P);
  hipLaunchKernelGGL(edge_kernel, dim3(2048), dim3(256), 0, stream, idx, P, W2, b2, out);
}